// Round 2
// baseline (426.297 us; speedup 1.0000x reference)
//
#include <hip/hip_runtime.h>

// FinePreprocess: gather 5x5 windows (stride 4, pad 2) from two NCHW fp32
// feature maps at M random (batch, grid-idx) points.
// Output flat layout (per map): (M, C, 5, 5).
//
// R4: latency attack. R3 (sort + XCD chunking) got FETCH to the compulsory
// ~150 MB but sat at 2.1 TB/s combined (26% peak) -- latency/occupancy-bound,
// not byte-bound (R2 proved ~54 G line-ops/s is sustainable; R3 ran at 34 G).
// Fixes:
//   - no LDS, no barrier: direct stores. A wave's 64 lanes cover 1280
//     contiguous output bytes, so L2 write-combining yields full lines even
//     with per-lane 20-B stores (dwordx4 @ 4-B align + dword).
//   - persistent blocks: 3000 blocks x 4 sorted points, exact XCD partition
//     (3000 = 8*375; base = (b%8)*1500 + (b/8)*4) -> less churn, 6 blk/CU.
//   - software pipeline: issue point p+1 loads before point p stores.

#define MPTS 6000
#define NPTS (2 * MPTS)
#define NCH  128
#define FH   240
#define FW   320
#define OUTW 80                 // (320 + 2*2 - 5)/4 + 1
#define OUTH 60
#define NKEY (2 * 4 * OUTH)     // 480 buckets: (map, b, gy)
#define PTFLOATS (NCH * 25)     // 3200 floats = 12.8 KB per (map, point)

#define PTS_PER_BLK 4
#define NBLK (NPTS / PTS_PER_BLK)   // 3000 = 8 * 375 -> exact XCD partition
#define PER_XCD (NPTS / 8)          // 1500

// workspace layout (in ints)
#define WS_HIST   0             // [480]  histogram
#define WS_CURSOR 512           // [480]  scatter cursors
#define WS_BASE   1024          // [481]  exclusive-scan bases
#define WS_ORDER  2048          // [12000] sorted job ids (map*MPTS + m)
#define WS_INTS   (WS_ORDER + NPTS)

typedef float f4_t __attribute__((ext_vector_type(4)));
typedef f4_t uf4 __attribute__((aligned(4)));   // 4-B-aligned dwordx4 stores

__device__ __forceinline__ int point_key(int map, int b, int gy) {
    return (map * 4 + b) * OUTH + gy;
}

// ---- tiny sort pipeline ---------------------------------------------------

__global__ void k_zero(int* __restrict__ ws) {
    const int t = threadIdx.x;          // launched with 1024 threads
    if (t < WS_BASE) ws[t] = 0;         // zeroes hist + cursor regions
}

__global__ void k_hist(const int* __restrict__ b_ids,
                       const int* __restrict__ i_ids,
                       const int* __restrict__ j_ids,
                       int* __restrict__ ws) {
    const int t = blockIdx.x * blockDim.x + threadIdx.x;
    if (t >= NPTS) return;
    const int map = t >= MPTS;
    const int m   = map ? t - MPTS : t;
    const int idx = map ? j_ids[m] : i_ids[m];
    const int gy  = idx / OUTW;
    atomicAdd(&ws[WS_HIST + point_key(map, b_ids[m], gy)], 1);
}

__global__ void k_scan(int* __restrict__ ws) {
    __shared__ int h[NKEY];
    const int t = threadIdx.x;
    for (int i = t; i < NKEY; i += blockDim.x) h[i] = ws[WS_HIST + i];
    __syncthreads();
    if (t == 0) {
        int acc = 0;
        for (int i = 0; i < NKEY; i++) { int v = h[i]; h[i] = acc; acc += v; }
    }
    __syncthreads();
    for (int i = t; i < NKEY; i += blockDim.x) ws[WS_BASE + i] = h[i];
    if (t == 0) ws[WS_BASE + NKEY] = NPTS;
}

__global__ void k_scatter(const int* __restrict__ b_ids,
                          const int* __restrict__ i_ids,
                          const int* __restrict__ j_ids,
                          int* __restrict__ ws) {
    const int t = blockIdx.x * blockDim.x + threadIdx.x;
    if (t >= NPTS) return;
    const int map = t >= MPTS;
    const int m   = map ? t - MPTS : t;
    const int idx = map ? j_ids[m] : i_ids[m];
    const int gy  = idx / OUTW;
    const int key = point_key(map, b_ids[m], gy);
    const int pos = atomicAdd(&ws[WS_CURSOR + key], 1);
    ws[WS_ORDER + ws[WS_BASE + key] + pos] = t;
}

// ---- main gather ----------------------------------------------------------

__device__ __forceinline__ void load_point(
    const float* __restrict__ f0, const float* __restrict__ f1,
    const int* __restrict__ b_ids, const int* __restrict__ i_ids,
    const int* __restrict__ j_ids, const int* __restrict__ order,
    int pos, int t, long& obase, float v[2][5])
{
    const int ent = order ? order[pos] : pos;      // pos is block-uniform -> s_load
    const int map = ent >= MPTS;
    const int m   = map ? ent - MPTS : ent;
    const float* __restrict__ feat = map ? f1 : f0;
    const int idx = map ? j_ids[m] : i_ids[m];
    const int b   = b_ids[m];

    const int gy = idx / OUTW;
    const int gx = idx - gy * OUTW;
    const int row0 = gy * 4 - 2;            // top row of window (may be -2,-1)
    const int col0 = gx * 4 - 2;            // left col (even; OOB only if gx==0)
    obase = (long)ent * PTFLOATS;

    // 640 segments (c=0..127, r=0..4), 2 per thread; 5 contiguous floats each.
    // Max col touched: 79*4-2+4 = 318 < 320 -> only the LEFT edge can be OOB.
#pragma unroll
    for (int it = 0; it < 2; it++) {
        const int s = t + it * 320;
        const int c = s / 5;
        const int r = s - c * 5;
        const int row = row0 + r;
        const bool vrow = (row >= 0) & (row < FH);
        const float* src = feat + (((long)(b * NCH + c) * FH + row) * FW + col0);

        if (vrow && (col0 >= 0)) {
            // col0 >= 0 implies gx >= 1 implies col0 >= 2 -> (src-2) is
            // 16-B aligned and in-bounds: two float4 loads cover cols
            // col0-2 .. col0+5 (max 319 at gx=79).
            const float4* p = (const float4*)(src - 2);
            const float4 q0 = p[0];
            const float4 q1 = p[1];
            v[it][0] = q0.z; v[it][1] = q0.w;
            v[it][2] = q1.x; v[it][3] = q1.y; v[it][4] = q1.z;
        } else {
#pragma unroll
            for (int k = 0; k < 5; k++) {
                const int cc = col0 + k;
                v[it][k] = (vrow && cc >= 0) ? src[k] : 0.0f;
            }
        }
    }
}

__device__ __forceinline__ void store_point(
    float* __restrict__ out, long obase, int t, const float v[2][5])
{
#pragma unroll
    for (int it = 0; it < 2; it++) {
        const int s = t + it * 320;
        float* dst = out + obase + (long)s * 5;
        uf4 q;
        q.x = v[it][0]; q.y = v[it][1]; q.z = v[it][2]; q.w = v[it][3];
        *(uf4*)dst = q;                 // global_store_dwordx4 (4-B aligned)
        dst[4] = v[it][4];              // global_store_dword
    }
}

__global__ __launch_bounds__(320, 7) void fine_gather_kernel(
    const float* __restrict__ f0, const float* __restrict__ f1,
    const int* __restrict__ b_ids, const int* __restrict__ i_ids,
    const int* __restrict__ j_ids, const int* __restrict__ order,
    float* __restrict__ out)
{
    const int blk = blockIdx.x;
    // Exact bijective XCD partition: with bid%8 round-robin dispatch, XCD x
    // processes sorted positions [x*1500, (x+1)*1500) in 4-point chunks.
    const int base_pos = (blk & 7) * PER_XCD + (blk >> 3) * PTS_PER_BLK;
    const int t = threadIdx.x;

    long obase_a; float va[2][5];
    load_point(f0, f1, b_ids, i_ids, j_ids, order, base_pos, t, obase_a, va);

#pragma unroll
    for (int p = 0; p < PTS_PER_BLK; p++) {
        long obase_b; float vb[2][5];
        if (p + 1 < PTS_PER_BLK) {
            // issue next point's scattered loads BEFORE this point's stores:
            // their latency hides under the store phase.
            load_point(f0, f1, b_ids, i_ids, j_ids, order,
                       base_pos + p + 1, t, obase_b, vb);
        }
        store_point(out, obase_a, t, va);
        if (p + 1 < PTS_PER_BLK) {
            obase_a = obase_b;
#pragma unroll
            for (int it = 0; it < 2; it++)
#pragma unroll
                for (int k = 0; k < 5; k++) va[it][k] = vb[it][k];
        }
    }
}

// ---- launch ---------------------------------------------------------------

extern "C" void kernel_launch(void* const* d_in, const int* in_sizes, int n_in,
                              void* d_out, int out_size, void* d_ws, size_t ws_size,
                              hipStream_t stream) {
    const float* f0   = (const float*)d_in[0];
    const float* f1   = (const float*)d_in[1];
    // d_in[2] = hw0_f, d_in[3] = hw0_c — compile-time constants, unused
    const int* b_ids  = (const int*)d_in[4];
    const int* i_ids  = (const int*)d_in[5];
    const int* j_ids  = (const int*)d_in[6];
    float* out        = (float*)d_out;

    int* ws = (int*)d_ws;
    const bool have_ws = (ws != nullptr) && (ws_size >= (size_t)WS_INTS * sizeof(int));

    const int* order = nullptr;
    if (have_ws) {
        k_zero<<<1, 1024, 0, stream>>>(ws);
        k_hist<<<(NPTS + 255) / 256, 256, 0, stream>>>(b_ids, i_ids, j_ids, ws);
        k_scan<<<1, 512, 0, stream>>>(ws);
        k_scatter<<<(NPTS + 255) / 256, 256, 0, stream>>>(b_ids, i_ids, j_ids, ws);
        order = ws + WS_ORDER;
    }

    fine_gather_kernel<<<NBLK, 320, 0, stream>>>(f0, f1, b_ids, i_ids, j_ids, order, out);
}